// Round 17
// baseline (2525.918 us; speedup 1.0000x reference)
//
#include <hip/hip_runtime.h>
#include <hip/hip_bf16.h>
#include <math.h>

#define BB 8
#define NN 200000
#define CC 81
#define TOPK 200
#define NBIN 4096
#define NPART 16
#define SLICE (NN / NPART)     // 12500
#define SL4 (SLICE / 4)        // 3125
#define LCAP2 1024
#define MTOT (NPART * TOPK)    // 3200

static __device__ __forceinline__ int bin_of(unsigned key) {
    // score in [1/81, 1] -> exponent in [120,127]; bits above bit 25 constant.
    // 12-bit monotone bin: exp low-3 bits + top-9 mantissa bits.
    return (int)((key >> 14) & (NBIN - 1));
}

// ---------------------------------------------------------------------------
// Kernel A (v4, proven 89.6us @ ~92% achievable HBM, unchanged since R10).
// ---------------------------------------------------------------------------
__global__ __launch_bounds__(256) void scores_kernel(const float* __restrict__ logits,
                                                     float* __restrict__ scores) {
    __shared__ float ls[64 * CC];     // 5184 floats = 20.7 KB
    __shared__ float lsc[64];
    int tid = threadIdx.x;
    int b = blockIdx.y;
    size_t fbase = ((size_t)b * NN + (size_t)blockIdx.x * 64) * CC;  // 16B-aligned
    const float4* g4 = (const float4*)(logits + fbase);
    float4* l4 = (float4*)ls;

    int wbase = tid & ~63;            // wave-uniform base within block
#pragma unroll
    for (int k = 0; k < 5; ++k) {     // 5 full wave rounds = 1280 float4s
        __builtin_amdgcn_global_load_lds(
            (const __attribute__((address_space(1))) void*)(g4 + k * 256 + tid),
            (__attribute__((address_space(3))) void*)(l4 + k * 256 + wbase),
            16, 0, 0);
    }
    if (tid < 16) l4[1280 + tid] = g4[1280 + tid];   // tail 16 f4s, plain copy
    __syncthreads();                  // drains vmcnt incl. global_load_lds

    int r = tid >> 2;                 // row 0..63
    int q = tid & 3;                  // quarter
    const float* row = ls + r * CC;
    int head = (4 - (r & 3)) & 3;     // floats until 16B alignment (81r%4==r%4)
    int nf4 = (CC - head) >> 2;       // 19 or 20 aligned float4s
    int tail = CC - head - 4 * nf4;   // 0..3

    float m = -INFINITY, S = 0.0f;
    const float4* rp = (const float4*)(row + head);
    for (int j = q; j < nf4; j += 4) {
        float4 v = rp[j];
        m = fmaxf(fmaxf(fmaxf(m, v.x), v.y), fmaxf(v.z, v.w));
        S += __expf(v.x) + __expf(v.y) + __expf(v.z) + __expf(v.w);
    }
    if (q == 3) {
        for (int h2 = 0; h2 < head; ++h2) { float x = row[h2]; m = fmaxf(m, x); S += __expf(x); }
        for (int t2 = 0; t2 < tail; ++t2) { float x = row[CC - tail + t2]; m = fmaxf(m, x); S += __expf(x); }
    }
#pragma unroll
    for (int w = 1; w < 4; w <<= 1) {
        m = fmaxf(m, __shfl_xor(m, w, 64));
        S += __shfl_xor(S, w, 64);
    }
    if (q == 0) lsc[r] = __expf(m) / S;
    __syncthreads();
    if (tid < 64) scores[(size_t)b * NN + (size_t)blockIdx.x * 64 + tid] = lsc[tid];
}

// ---------------------------------------------------------------------------
// Kernel L (unchanged from R16, passed): per-slice EXACT local top-200.
// grid (NPART, BB), 256 threads. Fully block-local.
// ---------------------------------------------------------------------------
__global__ __launch_bounds__(256) void localsel_kernel(const float* __restrict__ scores,
                                                       unsigned long long* __restrict__ lcand) {
    __shared__ unsigned h[NBIN];
    __shared__ unsigned csum[256];
    __shared__ int s_t, lcnt;
    __shared__ unsigned long long cbuf[LCAP2];

    int tid = threadIdx.x;
    int bx = blockIdx.x;
    int b = blockIdx.y;
    int base_idx = bx * SLICE;
    const float4* sc4 = (const float4*)(scores + (size_t)b * NN) + (size_t)bx * SL4;

    for (int i = tid; i < NBIN; i += 256) h[i] = 0u;
    if (tid == 0) lcnt = 0;
    __syncthreads();

    for (int i = tid; i < SL4; i += 256) {
        float4 v = sc4[i];
        atomicAdd(&h[bin_of(__float_as_uint(v.x))], 1u);
        atomicAdd(&h[bin_of(__float_as_uint(v.y))], 1u);
        atomicAdd(&h[bin_of(__float_as_uint(v.z))], 1u);
        atomicAdd(&h[bin_of(__float_as_uint(v.w))], 1u);
    }
    __syncthreads();

    int hi = NBIN - 1 - 16 * tid;
    unsigned s = 0;
#pragma unroll
    for (int j = 0; j < 16; ++j) s += h[hi - j];
    csum[tid] = s;
    __syncthreads();
    if (tid == 0) {
        unsigned run = 0;
        for (int t = 0; t < 256; ++t) { unsigned tmp = csum[t]; csum[t] = run; run += tmp; }
    }
    __syncthreads();
    unsigned before = csum[tid];
    if (before < TOPK && before + s >= TOPK) {
        unsigned cum = before;
        for (int j = 0; j < 16; ++j) {
            cum += h[hi - j];
            if (cum >= TOPK) { s_t = hi - j; break; }
        }
    }
    __syncthreads();
    int t = s_t;

    for (int i = tid; i < SL4; i += 256) {
        float4 v = sc4[i];
        unsigned keys[4] = { __float_as_uint(v.x), __float_as_uint(v.y),
                             __float_as_uint(v.z), __float_as_uint(v.w) };
#pragma unroll
        for (int j = 0; j < 4; ++j) {
            if (bin_of(keys[j]) >= t) {
                int p = atomicAdd(&lcnt, 1);
                if (p < LCAP2)
                    cbuf[p] = ((unsigned long long)keys[j] << 32) |
                              (unsigned)(base_idx + 4 * i + j);
            }
        }
    }
    __syncthreads();
    int M = lcnt;
    unsigned long long* outp = lcand + ((size_t)b * NPART + bx) * TOPK;

    if (M <= LCAP2) {
        for (int j = tid; j < M; j += 256) {
            unsigned long long pj = cbuf[j];
            unsigned kj = (unsigned)(pj >> 32);
            unsigned ij = (unsigned)pj;
            int rank = 0;
            for (int mm = 0; mm < M; ++mm) {
                unsigned long long pm = cbuf[mm];
                unsigned km = (unsigned)(pm >> 32);
                rank += (km > kj) || (km == kj && (unsigned)pm > ij);
            }
            if (rank < TOPK) outp[rank] = pj;
        }
    } else {
        const float* scb = scores + (size_t)b * NN + base_idx;
        for (int jj = tid; jj < SLICE; jj += 256) {
            unsigned kj = __float_as_uint(scb[jj]);
            int rank = 0;
            for (int mm = 0; mm < SLICE; ++mm) {
                unsigned km = __float_as_uint(scb[mm]);
                rank += (km > kj) || (km == kj && mm > jj);
            }
            if (rank < TOPK)
                outp[rank] = ((unsigned long long)kj << 32) | (unsigned)(base_idx + jj);
        }
    }
}

// ---------------------------------------------------------------------------
// Kernel F (v2): SAME logic as R16's final, but 256 THREADS. R16 profiled
// this kernel at 700us with VGPR_Count=16: __launch_bounds__(1024) starved
// the register allocator and the NMS loop's live state (4x u64 masks + 8
// floats) spilled to scratch -- a ~200-iteration loop-carried scratch
// dependency chain. At 256 threads the budget quadruples; no spill.
// ---------------------------------------------------------------------------
__global__ __launch_bounds__(256) void final_kernel(const float* __restrict__ segs,
                                                    const unsigned long long* __restrict__ lcand,
                                                    int* __restrict__ out) {
    __shared__ unsigned ck[MTOT];
    __shared__ int ci[MTOT];
    __shared__ unsigned fk[MTOT];
    __shared__ int fi[MTOT];
    __shared__ unsigned s_T;
    __shared__ int s_cnt;
    __shared__ unsigned sel_k[TOPK];
    __shared__ int sel_i[TOPK];
    __shared__ int nms_i[TOPK];
    __shared__ float nms_x1[TOPK + 56], nms_x2[TOPK + 56];

    int b = blockIdx.x;
    int tid = threadIdx.x;
    const float* sg = segs + (size_t)b * NN * 2;
    const unsigned long long* lc = lcand + (size_t)b * MTOT;

    for (int j = tid; j < MTOT; j += 256) {
        unsigned long long p = lc[j];
        ck[j] = (unsigned)(p >> 32);
        ci[j] = (int)(p & 0xffffffffull);
    }
    for (int i = tid; i < TOPK; i += 256) {
        out[b * TOPK + i] = 0;
        out[(BB + b) * TOPK + i] = 0;
    }
    for (int i = tid; i < 56; i += 256) { nms_x1[TOPK + i] = 0.f; nms_x2[TOPK + i] = 0.f; }
    if (tid == 0) s_cnt = 0;
    __syncthreads();

    // exact prune bound: T* = max over slices of the slice-200th key
    if (tid == 0) {
        unsigned mx = 0;
        for (int p = 0; p < NPART; ++p) {
            unsigned k199 = ck[p * TOPK + TOPK - 1];
            if (k199 > mx) mx = k199;
        }
        s_T = mx;
    }
    __syncthreads();
    unsigned T = s_T;

    for (int j = tid; j < MTOT; j += 256) {
        if (ck[j] >= T) {
            int p = atomicAdd(&s_cnt, 1);
            fk[p] = ck[j];
            fi[p] = ci[j];
        }
    }
    __syncthreads();
    int M2 = s_cnt;    // >= 200 guaranteed (the T*-achieving slice has 200)

    // exact top-200 by (key desc, idx desc) == stable argsort tail rule
    for (int j = tid; j < M2; j += 256) {
        unsigned kj = fk[j];
        int ij = fi[j];
        int rank = 0;
        for (int mm = 0; mm < M2; ++mm) {
            unsigned km = fk[mm];
            rank += (km > kj) || (km == kj && fi[mm] > ij);
        }
        if (rank < TOPK) { sel_k[rank] = kj; sel_i[rank] = ij; }
    }
    __syncthreads();

    // re-rank into NMS priority order (key desc, idx asc) == argmax tie rule
    if (tid < TOPK) {
        unsigned kj = sel_k[tid];
        int ij = sel_i[tid];
        int r2 = 0;
        for (int mm = 0; mm < TOPK; ++mm) {
            unsigned km = sel_k[mm];
            r2 += (km > kj) || (km == kj && sel_i[mm] < ij);
        }
        nms_i[r2] = ij;
        nms_x1[r2] = sg[2 * (size_t)ij];
        nms_x2[r2] = sg[2 * (size_t)ij + 1];
    }
    __syncthreads();

    // mask-scan greedy NMS on wave 0
    if (tid >= 64) return;
    int lane = tid;
    float rx1[4], rx2[4];
#pragma unroll
    for (int k = 0; k < 4; ++k) {
        rx1[k] = nms_x1[k * 64 + lane];
        rx2[k] = nms_x2[k * 64 + lane];
    }
    unsigned long long m0 = ~0ull, m1 = ~0ull, m2 = ~0ull, m3 = 0xffull;

    int* keep = out + b * TOPK;
    for (int it = 0; it < TOPK; ++it) {
        int p;
        if (m0)      p = __ffsll(m0) - 1;
        else if (m1) p = 64 + __ffsll(m1) - 1;
        else if (m2) p = 128 + __ffsll(m2) - 1;
        else if (m3) p = 192 + __ffsll(m3) - 1;
        else break;

        float wx1 = nms_x1[p];
        float wx2 = nms_x2[p];
        if (lane == 0) keep[it] = nms_i[p];

        unsigned long long mw[4] = { m0, m1, m2, m3 };
        unsigned long long nm[4];
#pragma unroll
        for (int k = 0; k < 4; ++k) {
            bool alive = (mw[k] >> lane) & 1ull;
            bool kill = false;
            if (alive) {
                int pos = k * 64 + lane;
                if (pos == p) kill = true;
                else {
                    float inter = fminf(rx2[k], wx2) - fmaxf(rx1[k], wx1);
                    kill = inter > 0.f;
                }
            }
            nm[k] = __ballot(alive && !kill);
        }
        m0 = nm[0]; m1 = nm[1]; m2 = nm[2]; m3 = nm[3];
    }
}

extern "C" void kernel_launch(void* const* d_in, const int* in_sizes, int n_in,
                              void* d_out, int out_size, void* d_ws, size_t ws_size,
                              hipStream_t stream) {
    const float* logits = (const float*)d_in[0];   // (8, 200000, 81) f32
    const float* segs   = (const float*)d_in[1];   // (8, 200000, 2)  f32
    int* out = (int*)d_out;                        // (16, 200) int32

    char* ws = (char*)d_ws;
    float*              scores = (float*)ws;                          // 6,400,000 B
    unsigned long long* lcand  = (unsigned long long*)(ws + 6400000); // 204,800 B

    dim3 sgrid(NN / 64, BB);                       // 3125 x 8
    scores_kernel<<<sgrid, 256, 0, stream>>>(logits, scores);
    dim3 lgrid(NPART, BB);                         // 16 x 8
    localsel_kernel<<<lgrid, 256, 0, stream>>>(scores, lcand);
    final_kernel<<<BB, 256, 0, stream>>>(segs, lcand, out);
}

// Round 18
// 206.113 us; speedup vs baseline: 12.2550x; 12.2550x over previous
//
#include <hip/hip_runtime.h>
#include <hip/hip_bf16.h>
#include <math.h>

#define BB 8
#define NN 200000
#define CC 81
#define TOPK 200
#define NBIN 4096
#define NPART 16
#define SLICE (NN / NPART)     // 12500
#define SL4 (SLICE / 4)        // 3125
#define LCAP2 1024
#define MTOT (NPART * TOPK)    // 3200
#define SUBK 13                // ceil(TOPK/NPART)
#define SUBN (NPART * SUBK)    // 208

static __device__ __forceinline__ int bin_of(unsigned key) {
    // score in [1/81, 1] -> exponent in [120,127]; bits above bit 25 constant.
    // 12-bit monotone bin: exp low-3 bits + top-9 mantissa bits.
    return (int)((key >> 14) & (NBIN - 1));
}

// ---------------------------------------------------------------------------
// Kernel A (v4, proven 89.6us @ ~92% achievable HBM, unchanged since R10).
// ---------------------------------------------------------------------------
__global__ __launch_bounds__(256) void scores_kernel(const float* __restrict__ logits,
                                                     float* __restrict__ scores) {
    __shared__ float ls[64 * CC];     // 5184 floats = 20.7 KB
    __shared__ float lsc[64];
    int tid = threadIdx.x;
    int b = blockIdx.y;
    size_t fbase = ((size_t)b * NN + (size_t)blockIdx.x * 64) * CC;  // 16B-aligned
    const float4* g4 = (const float4*)(logits + fbase);
    float4* l4 = (float4*)ls;

    int wbase = tid & ~63;            // wave-uniform base within block
#pragma unroll
    for (int k = 0; k < 5; ++k) {     // 5 full wave rounds = 1280 float4s
        __builtin_amdgcn_global_load_lds(
            (const __attribute__((address_space(1))) void*)(g4 + k * 256 + tid),
            (__attribute__((address_space(3))) void*)(l4 + k * 256 + wbase),
            16, 0, 0);
    }
    if (tid < 16) l4[1280 + tid] = g4[1280 + tid];   // tail 16 f4s, plain copy
    __syncthreads();                  // drains vmcnt incl. global_load_lds

    int r = tid >> 2;                 // row 0..63
    int q = tid & 3;                  // quarter
    const float* row = ls + r * CC;
    int head = (4 - (r & 3)) & 3;     // floats until 16B alignment (81r%4==r%4)
    int nf4 = (CC - head) >> 2;       // 19 or 20 aligned float4s
    int tail = CC - head - 4 * nf4;   // 0..3

    float m = -INFINITY, S = 0.0f;
    const float4* rp = (const float4*)(row + head);
    for (int j = q; j < nf4; j += 4) {
        float4 v = rp[j];
        m = fmaxf(fmaxf(fmaxf(m, v.x), v.y), fmaxf(v.z, v.w));
        S += __expf(v.x) + __expf(v.y) + __expf(v.z) + __expf(v.w);
    }
    if (q == 3) {
        for (int h2 = 0; h2 < head; ++h2) { float x = row[h2]; m = fmaxf(m, x); S += __expf(x); }
        for (int t2 = 0; t2 < tail; ++t2) { float x = row[CC - tail + t2]; m = fmaxf(m, x); S += __expf(x); }
    }
#pragma unroll
    for (int w = 1; w < 4; w <<= 1) {
        m = fmaxf(m, __shfl_xor(m, w, 64));
        S += __shfl_xor(S, w, 64);
    }
    if (q == 0) lsc[r] = __expf(m) / S;
    __syncthreads();
    if (tid < 64) scores[(size_t)b * NN + (size_t)blockIdx.x * 64 + tid] = lsc[tid];
}

// ---------------------------------------------------------------------------
// Kernel L (unchanged, passed R16/R17): per-slice EXACT local top-200,
// sorted descending by (key desc, idx desc). grid (NPART, BB), 256 threads.
// ---------------------------------------------------------------------------
__global__ __launch_bounds__(256) void localsel_kernel(const float* __restrict__ scores,
                                                       unsigned long long* __restrict__ lcand) {
    __shared__ unsigned h[NBIN];
    __shared__ unsigned csum[256];
    __shared__ int s_t, lcnt;
    __shared__ unsigned long long cbuf[LCAP2];

    int tid = threadIdx.x;
    int bx = blockIdx.x;
    int b = blockIdx.y;
    int base_idx = bx * SLICE;
    const float4* sc4 = (const float4*)(scores + (size_t)b * NN) + (size_t)bx * SL4;

    for (int i = tid; i < NBIN; i += 256) h[i] = 0u;
    if (tid == 0) lcnt = 0;
    __syncthreads();

    for (int i = tid; i < SL4; i += 256) {
        float4 v = sc4[i];
        atomicAdd(&h[bin_of(__float_as_uint(v.x))], 1u);
        atomicAdd(&h[bin_of(__float_as_uint(v.y))], 1u);
        atomicAdd(&h[bin_of(__float_as_uint(v.z))], 1u);
        atomicAdd(&h[bin_of(__float_as_uint(v.w))], 1u);
    }
    __syncthreads();

    int hi = NBIN - 1 - 16 * tid;
    unsigned s = 0;
#pragma unroll
    for (int j = 0; j < 16; ++j) s += h[hi - j];
    csum[tid] = s;
    __syncthreads();
    if (tid == 0) {
        unsigned run = 0;
        for (int t = 0; t < 256; ++t) { unsigned tmp = csum[t]; csum[t] = run; run += tmp; }
    }
    __syncthreads();
    unsigned before = csum[tid];
    if (before < TOPK && before + s >= TOPK) {
        unsigned cum = before;
        for (int j = 0; j < 16; ++j) {
            cum += h[hi - j];
            if (cum >= TOPK) { s_t = hi - j; break; }
        }
    }
    __syncthreads();
    int t = s_t;

    for (int i = tid; i < SL4; i += 256) {
        float4 v = sc4[i];
        unsigned keys[4] = { __float_as_uint(v.x), __float_as_uint(v.y),
                             __float_as_uint(v.z), __float_as_uint(v.w) };
#pragma unroll
        for (int j = 0; j < 4; ++j) {
            if (bin_of(keys[j]) >= t) {
                int p = atomicAdd(&lcnt, 1);
                if (p < LCAP2)
                    cbuf[p] = ((unsigned long long)keys[j] << 32) |
                              (unsigned)(base_idx + 4 * i + j);
            }
        }
    }
    __syncthreads();
    int M = lcnt;
    unsigned long long* outp = lcand + ((size_t)b * NPART + bx) * TOPK;

    if (M <= LCAP2) {
        for (int j = tid; j < M; j += 256) {
            unsigned long long pj = cbuf[j];
            unsigned kj = (unsigned)(pj >> 32);
            unsigned ij = (unsigned)pj;
            int rank = 0;
            for (int mm = 0; mm < M; ++mm) {
                unsigned long long pm = cbuf[mm];
                unsigned km = (unsigned)(pm >> 32);
                rank += (km > kj) || (km == kj && (unsigned)pm > ij);
            }
            if (rank < TOPK) outp[rank] = pj;
        }
    } else {
        const float* scb = scores + (size_t)b * NN + base_idx;
        for (int jj = tid; jj < SLICE; jj += 256) {
            unsigned kj = __float_as_uint(scb[jj]);
            int rank = 0;
            for (int mm = 0; mm < SLICE; ++mm) {
                unsigned km = __float_as_uint(scb[mm]);
                rank += (km > kj) || (km == kj && mm > jj);
            }
            if (rank < TOPK)
                outp[rank] = ((unsigned long long)kj << 32) | (unsigned)(base_idx + jj);
        }
    }
}

// ---------------------------------------------------------------------------
// Kernel F (v3): R17's prune (T* = max slice-200th) kept M2~2900 -> the
// O(M2^2) rank did ~8.5M serial LDS reads = the 2450us. New EXACT prune:
// T = key of the rank-199 element (by key desc, idx desc) of the 208-element
// subset {top-13 of each slice}. Subset is part of the full set, so the
// global 200th >= subset 200th -> all true top-200 have key >= T, and >=200
// elements survive. Expected survivors ~210-280 -> rank cost drops ~120x.
// 256 threads.
// ---------------------------------------------------------------------------
__global__ __launch_bounds__(256) void final_kernel(const float* __restrict__ segs,
                                                    const unsigned long long* __restrict__ lcand,
                                                    int* __restrict__ out) {
    __shared__ unsigned ck[MTOT];
    __shared__ int ci[MTOT];
    __shared__ unsigned tk[SUBN];
    __shared__ int ti[SUBN];
    __shared__ unsigned fk[MTOT];
    __shared__ int fi[MTOT];
    __shared__ unsigned s_T;
    __shared__ int s_cnt;
    __shared__ unsigned sel_k[TOPK];
    __shared__ int sel_i[TOPK];
    __shared__ int nms_i[TOPK];
    __shared__ float nms_x1[TOPK + 56], nms_x2[TOPK + 56];

    int b = blockIdx.x;
    int tid = threadIdx.x;
    const float* sg = segs + (size_t)b * NN * 2;
    const unsigned long long* lc = lcand + (size_t)b * MTOT;

    for (int j = tid; j < MTOT; j += 256) {
        unsigned long long p = lc[j];
        ck[j] = (unsigned)(p >> 32);
        ci[j] = (int)(p & 0xffffffffull);
    }
    for (int i = tid; i < TOPK; i += 256) {
        out[b * TOPK + i] = 0;
        out[(BB + b) * TOPK + i] = 0;
    }
    for (int i = tid; i < 56; i += 256) { nms_x1[TOPK + i] = 0.f; nms_x2[TOPK + i] = 0.f; }
    if (tid == 0) s_cnt = 0;
    __syncthreads();

    // build the 208-element subset: top-13 of each sorted slice list
    if (tid < SUBN) {
        int p = tid / SUBK, j = tid - p * SUBK;
        tk[tid] = ck[p * TOPK + j];
        ti[tid] = ci[p * TOPK + j];
    }
    __syncthreads();
    // exact rank within the subset; T = key of rank-199 (ranks dense+unique)
    if (tid < SUBN) {
        unsigned kj = tk[tid];
        int ij = ti[tid];
        int r = 0;
        for (int mm = 0; mm < SUBN; ++mm) {
            unsigned km = tk[mm];
            r += (km > kj) || (km == kj && ti[mm] > ij);
        }
        if (r == TOPK - 1) s_T = kj;
    }
    __syncthreads();
    unsigned T = s_T;

    // prune: survivors = all candidates with key >= T  (~210-280 expected)
    for (int j = tid; j < MTOT; j += 256) {
        if (ck[j] >= T) {
            int p = atomicAdd(&s_cnt, 1);
            fk[p] = ck[j];
            fi[p] = ci[j];
        }
    }
    __syncthreads();
    int M2 = s_cnt;    // >= 200 guaranteed

    // exact top-200 by (key desc, idx desc) == stable argsort tail rule
    for (int j = tid; j < M2; j += 256) {
        unsigned kj = fk[j];
        int ij = fi[j];
        int rank = 0;
        for (int mm = 0; mm < M2; ++mm) {
            unsigned km = fk[mm];
            rank += (km > kj) || (km == kj && fi[mm] > ij);
        }
        if (rank < TOPK) { sel_k[rank] = kj; sel_i[rank] = ij; }
    }
    __syncthreads();

    // re-rank into NMS priority order (key desc, idx asc) == argmax tie rule
    if (tid < TOPK) {
        unsigned kj = sel_k[tid];
        int ij = sel_i[tid];
        int r2 = 0;
        for (int mm = 0; mm < TOPK; ++mm) {
            unsigned km = sel_k[mm];
            r2 += (km > kj) || (km == kj && sel_i[mm] < ij);
        }
        nms_i[r2] = ij;
        nms_x1[r2] = sg[2 * (size_t)ij];
        nms_x2[r2] = sg[2 * (size_t)ij + 1];
    }
    __syncthreads();

    // mask-scan greedy NMS on wave 0 (proven)
    if (tid >= 64) return;
    int lane = tid;
    float rx1[4], rx2[4];
#pragma unroll
    for (int k = 0; k < 4; ++k) {
        rx1[k] = nms_x1[k * 64 + lane];
        rx2[k] = nms_x2[k * 64 + lane];
    }
    unsigned long long m0 = ~0ull, m1 = ~0ull, m2 = ~0ull, m3 = 0xffull;

    int* keep = out + b * TOPK;
    for (int it = 0; it < TOPK; ++it) {
        int p;
        if (m0)      p = __ffsll(m0) - 1;
        else if (m1) p = 64 + __ffsll(m1) - 1;
        else if (m2) p = 128 + __ffsll(m2) - 1;
        else if (m3) p = 192 + __ffsll(m3) - 1;
        else break;

        float wx1 = nms_x1[p];
        float wx2 = nms_x2[p];
        if (lane == 0) keep[it] = nms_i[p];

        unsigned long long mw[4] = { m0, m1, m2, m3 };
        unsigned long long nm[4];
#pragma unroll
        for (int k = 0; k < 4; ++k) {
            bool alive = (mw[k] >> lane) & 1ull;
            bool kill = false;
            if (alive) {
                int pos = k * 64 + lane;
                if (pos == p) kill = true;
                else {
                    float inter = fminf(rx2[k], wx2) - fmaxf(rx1[k], wx1);
                    kill = inter > 0.f;
                }
            }
            nm[k] = __ballot(alive && !kill);
        }
        m0 = nm[0]; m1 = nm[1]; m2 = nm[2]; m3 = nm[3];
    }
}

extern "C" void kernel_launch(void* const* d_in, const int* in_sizes, int n_in,
                              void* d_out, int out_size, void* d_ws, size_t ws_size,
                              hipStream_t stream) {
    const float* logits = (const float*)d_in[0];   // (8, 200000, 81) f32
    const float* segs   = (const float*)d_in[1];   // (8, 200000, 2)  f32
    int* out = (int*)d_out;                        // (16, 200) int32

    char* ws = (char*)d_ws;
    float*              scores = (float*)ws;                          // 6,400,000 B
    unsigned long long* lcand  = (unsigned long long*)(ws + 6400000); // 204,800 B

    dim3 sgrid(NN / 64, BB);                       // 3125 x 8
    scores_kernel<<<sgrid, 256, 0, stream>>>(logits, scores);
    dim3 lgrid(NPART, BB);                         // 16 x 8
    localsel_kernel<<<lgrid, 256, 0, stream>>>(scores, lcand);
    final_kernel<<<BB, 256, 0, stream>>>(segs, lcand, out);
}

// Round 19
// 173.554 us; speedup vs baseline: 14.5541x; 1.1876x over previous
//
#include <hip/hip_runtime.h>
#include <hip/hip_bf16.h>
#include <math.h>

#define BB 8
#define NN 200000
#define CC 81
#define TOPK 200
#define CAP 8192              // per-batch candidate capacity
#define FCAP 4096             // survivor capacity
#define NBIN 4096
#define THKEY 0x3E800000u     // bits of 0.25f (validated on this data by R13)

static __device__ __forceinline__ int bin_of(unsigned key) {
    // score in [1/81, 1] -> exponent in [120,127]; bits above bit 25 constant.
    // 12-bit monotone bin: exp low-3 bits + top-9 mantissa bits.
    return (int)((key >> 14) & (NBIN - 1));
}

// ---------------------------------------------------------------------------
// Kernel Z: zero the 8 per-batch counters (each on its own 128B line).
// ---------------------------------------------------------------------------
__global__ __launch_bounds__(64) void zero_kernel(int* __restrict__ cnt) {
    if (threadIdx.x < BB) cnt[threadIdx.x * 32] = 0;
}

// ---------------------------------------------------------------------------
// Kernel A (v4 + two-phase append): proven scores pipeline (89.6us, ~92% of
// achievable HBM) + prefilter: rows with key >= bits(0.25) are collected in
// an LDS buffer; ONE global atomicAdd per non-empty block reserves a range
// (R15's two-phase pattern -- R13's per-candidate RMWs on hot lines were the
// 300us disaster, NOT the threshold). ~690 RMWs/batch-line over 90us: hidden.
// grid = (NN/64, BB) = (3125, 8), block = 256.
// ---------------------------------------------------------------------------
__global__ __launch_bounds__(256) void scores_kernel(const float* __restrict__ logits,
                                                     float* __restrict__ scores,
                                                     unsigned long long* __restrict__ cand,
                                                     int* __restrict__ cnt) {
    __shared__ float ls[64 * CC];     // 5184 floats = 20.7 KB
    __shared__ float lsc[64];
    __shared__ unsigned long long lbuf[64];
    __shared__ int s_app, s_base;
    int tid = threadIdx.x;
    int b = blockIdx.y;
    if (tid == 0) s_app = 0;
    size_t fbase = ((size_t)b * NN + (size_t)blockIdx.x * 64) * CC;  // 16B-aligned
    const float4* g4 = (const float4*)(logits + fbase);
    float4* l4 = (float4*)ls;

    int wbase = tid & ~63;            // wave-uniform base within block
#pragma unroll
    for (int k = 0; k < 5; ++k) {     // 5 full wave rounds = 1280 float4s
        __builtin_amdgcn_global_load_lds(
            (const __attribute__((address_space(1))) void*)(g4 + k * 256 + tid),
            (__attribute__((address_space(3))) void*)(l4 + k * 256 + wbase),
            16, 0, 0);
    }
    if (tid < 16) l4[1280 + tid] = g4[1280 + tid];   // tail 16 f4s, plain copy
    __syncthreads();                  // drains vmcnt incl. global_load_lds

    int r = tid >> 2;                 // row 0..63
    int q = tid & 3;                  // quarter
    const float* row = ls + r * CC;
    int head = (4 - (r & 3)) & 3;     // floats until 16B alignment (81r%4==r%4)
    int nf4 = (CC - head) >> 2;       // 19 or 20 aligned float4s
    int tail = CC - head - 4 * nf4;   // 0..3

    float m = -INFINITY, S = 0.0f;
    const float4* rp = (const float4*)(row + head);
    for (int j = q; j < nf4; j += 4) {
        float4 v = rp[j];
        m = fmaxf(fmaxf(fmaxf(m, v.x), v.y), fmaxf(v.z, v.w));
        S += __expf(v.x) + __expf(v.y) + __expf(v.z) + __expf(v.w);
    }
    if (q == 3) {
        for (int h2 = 0; h2 < head; ++h2) { float x = row[h2]; m = fmaxf(m, x); S += __expf(x); }
        for (int t2 = 0; t2 < tail; ++t2) { float x = row[CC - tail + t2]; m = fmaxf(m, x); S += __expf(x); }
    }
#pragma unroll
    for (int w = 1; w < 4; w <<= 1) {
        m = fmaxf(m, __shfl_xor(m, w, 64));
        S += __shfl_xor(S, w, 64);
    }
    if (q == 0) {
        float s = __expf(m) / S;
        lsc[r] = s;
        unsigned key = __float_as_uint(s);
        if (key >= THKEY) {
            int p = atomicAdd(&s_app, 1);        // LDS atomic, <=64 per block
            lbuf[p] = ((unsigned long long)key << 32) |
                      (unsigned)(blockIdx.x * 64 + r);
        }
    }
    __syncthreads();
    if (tid < 64) scores[(size_t)b * NN + (size_t)blockIdx.x * 64 + tid] = lsc[tid];
    int na = s_app;
    if (na > 0) {
        if (tid == 0) s_base = atomicAdd(&cnt[b * 32], na);   // ONE global RMW
        __syncthreads();
        if (tid < na) {
            int pos = s_base + tid;
            if (pos < CAP) cand[(size_t)b * CAP + pos] = lbuf[tid];
        }
    }
}

// ---------------------------------------------------------------------------
// Kernel F (final, one block per batch, 1024 threads):
//  FAST path (200 <= cnt <= CAP): load M~780 packed (key,idx) candidates --
//    keys embedded, no score re-read.
//  SLOW path (threshold wrong / overflow): full-scan hist+gather from scores
//    (proven R12 code). Correct unconditionally.
//  Common: LDS hist over M -> exact rank-200 bin -> survivors (~210) ->
//    exact rank (key desc, idx desc) -> re-rank (key desc, idx asc) ->
//    mask-scan NMS on wave 0. All proven components.
// ---------------------------------------------------------------------------
__global__ __launch_bounds__(1024) void final_kernel(const float* __restrict__ scores,
                                                     const float* __restrict__ segs,
                                                     const unsigned long long* __restrict__ cand,
                                                     const int* __restrict__ cnt,
                                                     int* __restrict__ out) {
    __shared__ unsigned k_key[CAP];       // 32 KB
    __shared__ int k_idx[CAP];            // 32 KB
    __shared__ unsigned h[NBIN];          // 16 KB
    __shared__ unsigned csum[256];
    __shared__ int s_t, s_cnt;
    __shared__ unsigned fk[FCAP];         // 16 KB
    __shared__ int fi[FCAP];              // 16 KB
    __shared__ unsigned sel_k[TOPK];
    __shared__ int sel_i[TOPK];
    __shared__ int nms_i[TOPK];
    __shared__ float nms_x1[TOPK + 56], nms_x2[TOPK + 56];

    int b = blockIdx.x;
    int tid = threadIdx.x;
    const float* sc = scores + (size_t)b * NN;
    const float* sg = segs + (size_t)b * NN * 2;

    for (int i = tid; i < TOPK; i += 1024) {
        out[b * TOPK + i] = 0;
        out[(BB + b) * TOPK + i] = 0;
    }
    for (int i = tid; i < 56; i += 1024) { nms_x1[TOPK + i] = 0.f; nms_x2[TOPK + i] = 0.f; }

    int c = cnt[b * 32];
    int M;
    if (c >= TOPK && c <= CAP) {
        // ---- FAST: compact candidate list, keys embedded ----
        M = c;
        for (int j = tid; j < M; j += 1024) {
            unsigned long long p = cand[(size_t)b * CAP + j];
            k_key[j] = (unsigned)(p >> 32);
            k_idx[j] = (int)(p & 0xffffffffull);
        }
        __syncthreads();
    } else {
        // ---- SLOW: full hist + threshold + gather from scores (proven R12) ----
        for (int i = tid; i < NBIN; i += 1024) h[i] = 0u;
        if (tid == 0) s_cnt = 0;
        __syncthreads();
        const float4* sc4 = (const float4*)sc;
        for (int i = tid; i < NN / 4; i += 1024) {
            float4 v = sc4[i];
            atomicAdd(&h[bin_of(__float_as_uint(v.x))], 1u);
            atomicAdd(&h[bin_of(__float_as_uint(v.y))], 1u);
            atomicAdd(&h[bin_of(__float_as_uint(v.z))], 1u);
            atomicAdd(&h[bin_of(__float_as_uint(v.w))], 1u);
        }
        __syncthreads();
        unsigned s = 0;
        int hi = 0;
        if (tid < 256) {
            hi = NBIN - 1 - 16 * tid;
#pragma unroll
            for (int j = 0; j < 16; ++j) s += h[hi - j];
            csum[tid] = s;
        }
        __syncthreads();
        if (tid == 0) {
            unsigned run = 0;
            for (int t = 0; t < 256; ++t) { unsigned tmp = csum[t]; csum[t] = run; run += tmp; }
        }
        __syncthreads();
        if (tid < 256) {
            unsigned before = csum[tid];
            if (before < TOPK && before + s >= TOPK) {
                unsigned cum = before;
                for (int j = 0; j < 16; ++j) {
                    cum += h[hi - j];
                    if (cum >= TOPK) { s_t = hi - j; break; }
                }
            }
        }
        __syncthreads();
        int t = s_t;
        for (int i = tid; i < NN / 4; i += 1024) {
            const float4* sc4b = (const float4*)sc;
            float4 v = sc4b[i];
            unsigned keys[4] = { __float_as_uint(v.x), __float_as_uint(v.y),
                                 __float_as_uint(v.z), __float_as_uint(v.w) };
#pragma unroll
            for (int j = 0; j < 4; ++j) {
                if (bin_of(keys[j]) >= t) {
                    int pos = atomicAdd(&s_cnt, 1);
                    if (pos < CAP) { k_key[pos] = keys[j]; k_idx[pos] = 4 * i + j; }
                }
            }
        }
        __syncthreads();
        M = s_cnt; if (M > CAP) M = CAP;
    }

    // ---- candidate-set hist -> exact rank-200 threshold bin ----
    for (int i = tid; i < NBIN; i += 1024) h[i] = 0u;
    if (tid == 0) s_cnt = 0;
    __syncthreads();
    for (int j = tid; j < M; j += 1024) atomicAdd(&h[bin_of(k_key[j])], 1u);
    __syncthreads();
    unsigned s2 = 0;
    int hi2 = 0;
    if (tid < 256) {
        hi2 = NBIN - 1 - 16 * tid;
#pragma unroll
        for (int j = 0; j < 16; ++j) s2 += h[hi2 - j];
        csum[tid] = s2;
    }
    __syncthreads();
    if (tid == 0) {
        unsigned run = 0;
        for (int t = 0; t < 256; ++t) { unsigned tmp = csum[t]; csum[t] = run; run += tmp; }
    }
    __syncthreads();
    if (tid < 256) {
        unsigned before = csum[tid];
        if (before < TOPK && before + s2 >= TOPK) {
            unsigned cum = before;
            for (int j = 0; j < 16; ++j) {
                cum += h[hi2 - j];
                if (cum >= TOPK) { s_t = hi2 - j; break; }
            }
        }
    }
    __syncthreads();
    int t2 = s_t;

    // ---- survivors (bin >= t2): ~205-300 expected ----
    for (int j = tid; j < M; j += 1024) {
        if (bin_of(k_key[j]) >= t2) {
            int p = atomicAdd(&s_cnt, 1);
            if (p < FCAP) { fk[p] = k_key[j]; fi[p] = k_idx[j]; }
        }
    }
    __syncthreads();
    int M2 = s_cnt; if (M2 > FCAP) M2 = FCAP;

    // ---- exact top-200 by (key desc, idx desc) == stable argsort tail ----
    for (int j = tid; j < M2; j += 1024) {
        unsigned kj = fk[j];
        int ij = fi[j];
        int rank = 0;
        for (int mm = 0; mm < M2; ++mm) {
            unsigned km = fk[mm];
            rank += (km > kj) || (km == kj && fi[mm] > ij);
        }
        if (rank < TOPK) { sel_k[rank] = kj; sel_i[rank] = ij; }
    }
    __syncthreads();

    // ---- re-rank into NMS priority order (key desc, idx asc) ----
    if (tid < TOPK) {
        unsigned kj = sel_k[tid];
        int ij = sel_i[tid];
        int r2 = 0;
        for (int mm = 0; mm < TOPK; ++mm) {
            unsigned km = sel_k[mm];
            r2 += (km > kj) || (km == kj && sel_i[mm] < ij);
        }
        nms_i[r2] = ij;
        nms_x1[r2] = sg[2 * (size_t)ij];
        nms_x2[r2] = sg[2 * (size_t)ij + 1];
    }
    __syncthreads();

    // ---- mask-scan greedy NMS on wave 0 (proven) ----
    if (tid >= 64) return;
    int lane = tid;
    float rx1[4], rx2[4];
#pragma unroll
    for (int k = 0; k < 4; ++k) {
        rx1[k] = nms_x1[k * 64 + lane];
        rx2[k] = nms_x2[k * 64 + lane];
    }
    unsigned long long m0 = ~0ull, m1 = ~0ull, m2 = ~0ull, m3 = 0xffull;

    int* keep = out + b * TOPK;
    for (int it = 0; it < TOPK; ++it) {
        int p;
        if (m0)      p = __ffsll(m0) - 1;
        else if (m1) p = 64 + __ffsll(m1) - 1;
        else if (m2) p = 128 + __ffsll(m2) - 1;
        else if (m3) p = 192 + __ffsll(m3) - 1;
        else break;

        float wx1 = nms_x1[p];
        float wx2 = nms_x2[p];
        if (lane == 0) keep[it] = nms_i[p];

        unsigned long long mw[4] = { m0, m1, m2, m3 };
        unsigned long long nm[4];
#pragma unroll
        for (int k = 0; k < 4; ++k) {
            bool alive = (mw[k] >> lane) & 1ull;
            bool kill = false;
            if (alive) {
                int pos = k * 64 + lane;
                if (pos == p) kill = true;
                else {
                    float inter = fminf(rx2[k], wx2) - fmaxf(rx1[k], wx1);
                    kill = inter > 0.f;
                }
            }
            nm[k] = __ballot(alive && !kill);
        }
        m0 = nm[0]; m1 = nm[1]; m2 = nm[2]; m3 = nm[3];
    }
}

extern "C" void kernel_launch(void* const* d_in, const int* in_sizes, int n_in,
                              void* d_out, int out_size, void* d_ws, size_t ws_size,
                              hipStream_t stream) {
    const float* logits = (const float*)d_in[0];   // (8, 200000, 81) f32
    const float* segs   = (const float*)d_in[1];   // (8, 200000, 2)  f32
    int* out = (int*)d_out;                        // (16, 200) int32

    char* ws = (char*)d_ws;
    float*              scores = (float*)ws;                            // 6,400,000 B
    unsigned long long* cand   = (unsigned long long*)(ws + 6400000);   // 8*8192*8 = 524,288 B
    int*                cnt    = (int*)(ws + 6400000 + 524288);         // 8 lines (1 KB)

    zero_kernel<<<1, 64, 0, stream>>>(cnt);
    dim3 sgrid(NN / 64, BB);                       // 3125 x 8
    scores_kernel<<<sgrid, 256, 0, stream>>>(logits, scores, cand, cnt);
    final_kernel<<<BB, 1024, 0, stream>>>(scores, segs, cand, cnt, out);
}